// Round 4
// baseline (74.388 us; speedup 1.0000x reference)
//
#include <hip/hip_runtime.h>

// GAT: N=4096, F_IN=128, F_HID=64, H=4, F_OUT=64, alpha=0.2
#define GN 4096
#define F_IN 128
#define F_HID 64
#define NHEADS 4
#define F_OUT 64
#define ALPHA 0.2f
#define MAX_DEG 256

// workspace layout (bytes)
#define OFF_WH     0           // GN*256*4  = 4 MB   [i][head*64+f]
#define OFF_SRC1   4194304     // 4*GN*4
#define OFF_DST1   4259840     // 4*GN*4
#define OFF_HCAT   4325376     // GN*256*4  = 4 MB
#define OFF_WH2    8519680     // GN*64*4   = 1 MB
#define OFF_SRC2   9568256     // GN*4
#define OFF_DST2   9584640     // GN*4
#define OFF_CNT    9601024     // GN*4
#define OFF_IDX    9617408     // GN*MAX_DEG*4 = 4 MB

// ===== merged: adj compaction (blocks 0..1023) + lin/Wh/srcdst1 GEMMs (1024..1535) =====
__global__ __launch_bounds__(256) void prep_kernel(
        const float* __restrict__ adj, int* __restrict__ cnt, int* __restrict__ idx,
        const float* __restrict__ x, const float* __restrict__ linW,
        const float* __restrict__ linb, const float* __restrict__ Wheads,
        const float* __restrict__ aheads, float* __restrict__ Wh,
        float* __restrict__ src1, float* __restrict__ dst1) {
    __shared__ float xs[8][128];
    __shared__ float hs[8][128];
    const int tid = threadIdx.x;

    if (blockIdx.x < 1024) {
        // ---- neighbor compaction (ascending j), float4, pad-to-4 ----
        const int wave = tid >> 6;
        const int lane = tid & 63;
        const int row  = blockIdx.x * 4 + wave;
        const float4* a4 = (const float4*)(adj + (size_t)row * GN);
        int* out = idx + (size_t)row * MAX_DEG;
        const unsigned long long low = (lane == 0) ? 0ULL : ((1ULL << lane) - 1ULL);
        int count = 0;
        #pragma unroll 4
        for (int it = 0; it < GN / 256; ++it) {
            float4 v = a4[it * 64 + lane];
            bool b0 = v.x > 0.0f, b1 = v.y > 0.0f, b2 = v.z > 0.0f, b3 = v.w > 0.0f;
            unsigned long long m0 = __ballot(b0), m1 = __ballot(b1);
            unsigned long long m2 = __ballot(b2), m3 = __ballot(b3);
            int pos = count + __popcll(m0 & low) + __popcll(m1 & low)
                            + __popcll(m2 & low) + __popcll(m3 & low);
            int col = it * 256 + lane * 4;
            if (b0 && pos < MAX_DEG) out[pos] = col;     pos += b0;
            if (b1 && pos < MAX_DEG) out[pos] = col + 1; pos += b1;
            if (b2 && pos < MAX_DEG) out[pos] = col + 2; pos += b2;
            if (b3 && pos < MAX_DEG) out[pos] = col + 3; pos += b3;
            count += __popcll(m0) + __popcll(m1) + __popcll(m2) + __popcll(m3);
        }
        int cc = (count > MAX_DEG) ? MAX_DEG : count;
        int pad = ((cc + 3) & ~3) - cc;
        if (lane < pad) out[cc + lane] = 0;
        if (lane == 0) cnt[row] = cc;
        return;
    }

    // ---- fused GEMMs: h = x@linW+b ; Wh = h@W_heads ; src1/dst1 ----
    const int i0 = (blockIdx.x - 1024) * 8;
    #pragma unroll
    for (int t = 0; t < 4; ++t) {
        int e = t * 256 + tid;
        xs[e >> 7][e & 127] = x[(size_t)i0 * 128 + e];
    }
    __syncthreads();
    {
        const int k = tid & 127;
        const int n0 = tid >> 7;
        float bk = linb[k];
        float a0 = bk, a1 = bk, a2 = bk, a3 = bk;
        for (int j = 0; j < 128; ++j) {
            float w = linW[j * 128 + k];
            a0 += xs[n0][j] * w;
            a1 += xs[n0 + 2][j] * w;
            a2 += xs[n0 + 4][j] * w;
            a3 += xs[n0 + 6][j] * w;
        }
        hs[n0][k] = a0; hs[n0 + 2][k] = a1; hs[n0 + 4][k] = a2; hs[n0 + 6][k] = a3;
    }
    __syncthreads();
    const int hd = tid >> 6, f = tid & 63;
    float acc[8] = {0, 0, 0, 0, 0, 0, 0, 0};
    const float* Wp = Wheads + (size_t)hd * F_IN * F_HID + f;
    for (int j = 0; j < 128; ++j) {
        float w = Wp[j * 64];
        #pragma unroll
        for (int n = 0; n < 8; ++n) acc[n] += hs[n][j] * w;
    }
    const float as = aheads[hd * 128 + f];
    const float ad = aheads[hd * 128 + 64 + f];
    #pragma unroll
    for (int n = 0; n < 8; ++n) {
        Wh[(size_t)(i0 + n) * 256 + hd * 64 + f] = acc[n];
        float sv = acc[n] * as, dv = acc[n] * ad;
        #pragma unroll
        for (int o = 32; o > 0; o >>= 1) {
            sv += __shfl_xor(sv, o, 64);
            dv += __shfl_xor(dv, o, 64);
        }
        if (f == 0) { src1[hd * GN + i0 + n] = sv; dst1[hd * GN + i0 + n] = dv; }
    }
}

// ===== layer-1 attention: one wave per ROW (all 4 heads), float4 gathers =====
__global__ __launch_bounds__(256) void attn1_kernel(
        const float* __restrict__ Wh, const float* __restrict__ src,
        const float* __restrict__ dst, const int* __restrict__ cnt,
        const int* __restrict__ idx, float* __restrict__ hcat) {
    __shared__ float ps[4][4][260];     // [wave][head][neighbor], padded vs bank conflicts
    const int wave = threadIdx.x >> 6;
    const int lane = threadIdx.x & 63;
    const int row  = blockIdx.x * 4 + wave;
    const int deg  = cnt[row];
    const int* nb  = idx + (size_t)row * MAX_DEG;
    const int nchunk = (deg + 63) >> 6;     // 1 for deg<=64 (typical)

    // phase 1: per-head softmax weights (normalized), lanes over neighbors
    #pragma unroll
    for (int hd = 0; hd < 4; ++hd) {
        const float s_i = src[hd * GN + row];
        float e[4];
        float m = -1e30f;
        for (int c = 0; c < nchunk; ++c) {
            int t = c * 64 + lane;
            float ev = -1e30f;
            if (t < deg) {
                int j = nb[t];
                ev = s_i + dst[hd * GN + j];
                ev = (ev > 0.0f) ? ev : ALPHA * ev;
            }
            e[c] = ev; m = fmaxf(m, ev);
        }
        #pragma unroll
        for (int o = 32; o > 0; o >>= 1) m = fmaxf(m, __shfl_xor(m, o, 64));
        float l = 0.0f;
        for (int c = 0; c < nchunk; ++c) { e[c] = expf(e[c] - m); l += e[c]; }
        #pragma unroll
        for (int o = 32; o > 0; o >>= 1) l += __shfl_xor(l, o, 64);
        float inv = 1.0f / l;
        for (int c = 0; c < nchunk; ++c) ps[wave][hd][c * 64 + lane] = e[c] * inv;
    }
    // same wave produced ps[wave]; no cross-wave sharing -> no barrier needed

    // phase 2: lane's float4 covers features 4*lane..4*lane+3, all of head lane>>4
    const int hl = lane >> 4;
    const float4* Wh4 = (const float4*)Wh;
    float4 acc = make_float4(0.f, 0.f, 0.f, 0.f);
    const int deg4 = (deg + 3) & ~3;
    for (int t = 0; t < deg4; t += 4) {
        int4 jj = *(const int4*)(nb + t);
        float p0 = ps[wave][hl][t],     p1 = ps[wave][hl][t + 1];
        float p2 = ps[wave][hl][t + 2], p3 = ps[wave][hl][t + 3];
        float4 v0 = Wh4[(size_t)jj.x * 64 + lane];
        float4 v1 = Wh4[(size_t)jj.y * 64 + lane];
        float4 v2 = Wh4[(size_t)jj.z * 64 + lane];
        float4 v3 = Wh4[(size_t)jj.w * 64 + lane];
        acc.x += p0 * v0.x + p1 * v1.x + p2 * v2.x + p3 * v3.x;
        acc.y += p0 * v0.y + p1 * v1.y + p2 * v2.y + p3 * v3.y;
        acc.z += p0 * v0.z + p1 * v1.z + p2 * v2.z + p3 * v3.z;
        acc.w += p0 * v0.w + p1 * v1.w + p2 * v2.w + p3 * v3.w;
    }
    acc.x = (acc.x > 0.0f) ? acc.x : expm1f(acc.x);
    acc.y = (acc.y > 0.0f) ? acc.y : expm1f(acc.y);
    acc.z = (acc.z > 0.0f) ? acc.z : expm1f(acc.z);
    acc.w = (acc.w > 0.0f) ? acc.w : expm1f(acc.w);
    ((float4*)hcat)[(size_t)row * 64 + lane] = acc;
}

// ===== fused: Wh2 = hcat@W_end ; src2/dst2 =====
__global__ __launch_bounds__(256) void fused2_kernel(
        const float* __restrict__ hcat, const float* __restrict__ Wend,
        const float* __restrict__ aend, float* __restrict__ Wh2,
        float* __restrict__ src2, float* __restrict__ dst2) {
    __shared__ float cs[8][256];
    const int tid = threadIdx.x;
    const int i0  = blockIdx.x * 8;
    #pragma unroll
    for (int t = 0; t < 8; ++t) {
        int e = t * 256 + tid;
        cs[e >> 8][e & 255] = hcat[(size_t)i0 * 256 + e];
    }
    __syncthreads();
    const int f = tid & 63;
    const int n0 = tid >> 6;
    float a0 = 0.0f, a1 = 0.0f;
    const float* Wp = Wend + f;
    for (int j = 0; j < 256; ++j) {
        float w = Wp[j * 64];
        a0 += cs[n0][j] * w;
        a1 += cs[n0 + 4][j] * w;
    }
    const float as = aend[f];
    const float ad = aend[64 + f];
    Wh2[(size_t)(i0 + n0) * 64 + f] = a0;
    Wh2[(size_t)(i0 + n0 + 4) * 64 + f] = a1;
    float s0 = a0 * as, d0 = a0 * ad, s1 = a1 * as, d1 = a1 * ad;
    #pragma unroll
    for (int o = 32; o > 0; o >>= 1) {
        s0 += __shfl_xor(s0, o, 64); d0 += __shfl_xor(d0, o, 64);
        s1 += __shfl_xor(s1, o, 64); d1 += __shfl_xor(d1, o, 64);
    }
    if (f == 0) {
        src2[i0 + n0] = s0; dst2[i0 + n0] = d0;
        src2[i0 + n0 + 4] = s1; dst2[i0 + n0 + 4] = d1;
    }
}

// ===== layer-2 attention + elu + final row softmax; wave per row =====
__global__ __launch_bounds__(256) void attn2_kernel(
        const float* __restrict__ Wh2, const float* __restrict__ src,
        const float* __restrict__ dst, const int* __restrict__ cnt,
        const int* __restrict__ idx, float* __restrict__ out) {
    const int wave = threadIdx.x >> 6;
    const int lane = threadIdx.x & 63;
    const int row  = blockIdx.x * 4 + wave;
    const int deg = cnt[row];
    const int* nb = idx + (size_t)row * MAX_DEG;
    const float s_i = src[row];

    float e[4];
    #pragma unroll
    for (int c = 0; c < 4; ++c) {
        int t = c * 64 + lane;
        float ev = -1e30f;
        if (t < deg) {
            int j = nb[t];
            ev = s_i + dst[j];
            ev = (ev > 0.0f) ? ev : ALPHA * ev;
        }
        e[c] = ev;
    }
    float m = fmaxf(fmaxf(e[0], e[1]), fmaxf(e[2], e[3]));
    #pragma unroll
    for (int o = 32; o > 0; o >>= 1) m = fmaxf(m, __shfl_xor(m, o, 64));
    float l = 0.0f;
    #pragma unroll
    for (int c = 0; c < 4; ++c) { e[c] = expf(e[c] - m); l += e[c]; }
    #pragma unroll
    for (int o = 32; o > 0; o >>= 1) l += __shfl_xor(l, o, 64);

    float accA = 0.0f, accB = 0.0f;
    const float* W2 = Wh2 + lane;
    #pragma unroll
    for (int c = 0; c < 4; ++c) {
        int base = c * 64;
        if (base >= deg) break;
        int nmax = deg - base; if (nmax > 64) nmax = 64;
        int n4 = (nmax + 3) & ~3;
        for (int t = 0; t < n4; t += 4) {
            float p0 = __shfl(e[c], t, 64);
            float p1 = __shfl(e[c], t + 1, 64);
            float p2 = __shfl(e[c], t + 2, 64);
            float p3 = __shfl(e[c], t + 3, 64);
            int4 jj = *(const int4*)(nb + base + t);
            accA += p0 * W2[(size_t)jj.x * 64];
            accB += p1 * W2[(size_t)jj.y * 64];
            accA += p2 * W2[(size_t)jj.z * 64];
            accB += p3 * W2[(size_t)jj.w * 64];
        }
    }
    float v = (accA + accB) / l;
    v = (v > 0.0f) ? v : expm1f(v);      // elu

    float mm = v;
    #pragma unroll
    for (int o = 32; o > 0; o >>= 1) mm = fmaxf(mm, __shfl_xor(mm, o, 64));
    float ee = expf(v - mm);
    float ss = ee;
    #pragma unroll
    for (int o = 32; o > 0; o >>= 1) ss += __shfl_xor(ss, o, 64);
    out[(size_t)row * F_OUT + lane] = ee / ss;
}

extern "C" void kernel_launch(void* const* d_in, const int* in_sizes, int n_in,
                              void* d_out, int out_size, void* d_ws, size_t ws_size,
                              hipStream_t stream) {
    const float* x      = (const float*)d_in[0];
    const float* adj    = (const float*)d_in[1];
    const float* lin_W  = (const float*)d_in[2];
    const float* lin_b  = (const float*)d_in[3];
    const float* Wheads = (const float*)d_in[4];
    const float* aheads = (const float*)d_in[5];
    const float* Wend   = (const float*)d_in[6];
    const float* aend   = (const float*)d_in[7];
    float* out = (float*)d_out;

    char* ws = (char*)d_ws;
    float* Wh   = (float*)(ws + OFF_WH);
    float* src1 = (float*)(ws + OFF_SRC1);
    float* dst1 = (float*)(ws + OFF_DST1);
    float* hcat = (float*)(ws + OFF_HCAT);
    float* Wh2  = (float*)(ws + OFF_WH2);
    float* src2 = (float*)(ws + OFF_SRC2);
    float* dst2 = (float*)(ws + OFF_DST2);
    int*   cnt  = (int*)(ws + OFF_CNT);
    int*   nidx = (int*)(ws + OFF_IDX);

    // [adj compaction || lin+Wh+srcdst1] -> attn1 -> [Wh2+srcdst2] -> attn2
    prep_kernel<<<1024 + GN / 8, 256, 0, stream>>>(adj, cnt, nidx, x, lin_W, lin_b,
                                                   Wheads, aheads, Wh, src1, dst1);
    attn1_kernel<<<GN / 4, 256, 0, stream>>>(Wh, src1, dst1, cnt, nidx, hcat);
    fused2_kernel<<<GN / 8, 256, 0, stream>>>(hcat, Wend, aend, Wh2, src2, dst2);
    attn2_kernel<<<GN / 4, 256, 0, stream>>>(Wh2, src2, dst2, cnt, nidx, out);
}

// Round 5
// 69.649 us; speedup vs baseline: 1.0680x; 1.0680x over previous
//
#include <hip/hip_runtime.h>

// GAT: N=4096, F_IN=128, F_HID=64, H=4, F_OUT=64, alpha=0.2
#define GN 4096
#define F_IN 128
#define F_HID 64
#define NHEADS 4
#define F_OUT 64
#define ALPHA 0.2f
#define MAX_DEG 256

// workspace layout (bytes)
#define OFF_WH     0           // GN*256*4  = 4 MB   [i][head*64+f]
#define OFF_SRC1   4194304     // 4*GN*4
#define OFF_DST1   4259840     // 4*GN*4
#define OFF_HCAT   4325376     // GN*256*4  = 4 MB
#define OFF_WH2    8519680     // GN*64*4   = 1 MB
#define OFF_SRC2   9568256     // GN*4
#define OFF_DST2   9584640     // GN*4
#define OFF_CNT    9601024     // GN*4
#define OFF_IDX    9617408     // GN*MAX_DEG*4 = 4 MB

// ===== neighbor compaction: ONE BLOCK PER ROW, 4 strip-waves, LDS merge =====
// wave w compacts columns [w*1024, (w+1)*1024) into sidx[w][]; then prefix+copy.
__global__ __launch_bounds__(256) void build_nbr_kernel(const float* __restrict__ adj,
                                 int* __restrict__ cnt, int* __restrict__ idx) {
    __shared__ int sidx[4][264];
    __shared__ int scnt[4];
    const int wave = threadIdx.x >> 6;
    const int lane = threadIdx.x & 63;
    const int row  = blockIdx.x;
    const float4* a4 = (const float4*)(adj + (size_t)row * GN) + wave * 256;
    int count = 0;
    #pragma unroll
    for (int it = 0; it < 4; ++it) {
        float4 v = a4[it * 64 + lane];
        bool b0 = v.x > 0.0f, b1 = v.y > 0.0f, b2 = v.z > 0.0f, b3 = v.w > 0.0f;
        unsigned long long m0 = __ballot(b0), m1 = __ballot(b1);
        unsigned long long m2 = __ballot(b2), m3 = __ballot(b3);
        // within-mask prefix for this lane via mbcnt idiom
        int p0 = __builtin_amdgcn_mbcnt_hi((unsigned)(m0 >> 32), __builtin_amdgcn_mbcnt_lo((unsigned)m0, 0u));
        int p1 = __builtin_amdgcn_mbcnt_hi((unsigned)(m1 >> 32), __builtin_amdgcn_mbcnt_lo((unsigned)m1, 0u));
        int p2 = __builtin_amdgcn_mbcnt_hi((unsigned)(m2 >> 32), __builtin_amdgcn_mbcnt_lo((unsigned)m2, 0u));
        int p3 = __builtin_amdgcn_mbcnt_hi((unsigned)(m3 >> 32), __builtin_amdgcn_mbcnt_lo((unsigned)m3, 0u));
        int c0 = __popcll(m0), c1 = __popcll(m1), c2 = __popcll(m2), c3 = __popcll(m3);
        int col = wave * 1024 + it * 256 + lane * 4;
        int pos = count + p0;
        if (b0 && pos < 264) sidx[wave][pos] = col;
        pos = count + c0 + p1;
        if (b1 && pos < 264) sidx[wave][pos] = col + 1;
        pos = count + c0 + c1 + p2;
        if (b2 && pos < 264) sidx[wave][pos] = col + 2;
        pos = count + c0 + c1 + c2 + p3;
        if (b3 && pos < 264) sidx[wave][pos] = col + 3;
        count += c0 + c1 + c2 + c3;
    }
    if (lane == 0) scnt[wave] = count;
    __syncthreads();
    int base = 0;
    #pragma unroll
    for (int w = 0; w < 3; ++w) base += (w < wave) ? scnt[w] : 0;
    const int total = scnt[0] + scnt[1] + scnt[2] + scnt[3];
    const int cc = (total > MAX_DEG) ? MAX_DEG : total;
    int* outp = idx + (size_t)row * MAX_DEG;
    for (int t = lane; t < count; t += 64) {
        int pos = base + t;
        if (pos < MAX_DEG) outp[pos] = sidx[wave][t];
    }
    if (threadIdx.x < 4) {
        int pad = ((cc + 3) & ~3) - cc;
        if (threadIdx.x < pad) outp[cc + threadIdx.x] = 0;   // p will be exactly 0
        if (threadIdx.x == 0) cnt[row] = cc;
    }
}

// ===== fused: h = x@linW+b ; Wh = h@W_heads ; src1/dst1 ; 8 nodes/block =====
__global__ __launch_bounds__(256) void fused1_kernel(
        const float* __restrict__ x, const float* __restrict__ linW,
        const float* __restrict__ linb, const float* __restrict__ Wheads,
        const float* __restrict__ aheads, float* __restrict__ Wh,
        float* __restrict__ src1, float* __restrict__ dst1) {
    __shared__ float xs[8][128];
    __shared__ float hs[8][128];
    const int tid = threadIdx.x;
    const int i0  = blockIdx.x * 8;
    #pragma unroll
    for (int t = 0; t < 4; ++t) {
        int e = t * 256 + tid;
        xs[e >> 7][e & 127] = x[(size_t)i0 * 128 + e];
    }
    __syncthreads();
    {
        const int k = tid & 127;
        const int n0 = tid >> 7;
        float bk = linb[k];
        float a0 = bk, a1 = bk, a2 = bk, a3 = bk;
        for (int j = 0; j < 128; ++j) {
            float w = linW[j * 128 + k];
            a0 += xs[n0][j] * w;
            a1 += xs[n0 + 2][j] * w;
            a2 += xs[n0 + 4][j] * w;
            a3 += xs[n0 + 6][j] * w;
        }
        hs[n0][k] = a0; hs[n0 + 2][k] = a1; hs[n0 + 4][k] = a2; hs[n0 + 6][k] = a3;
    }
    __syncthreads();
    const int hd = tid >> 6, f = tid & 63;
    float acc[8] = {0, 0, 0, 0, 0, 0, 0, 0};
    const float* Wp = Wheads + (size_t)hd * F_IN * F_HID + f;
    for (int j = 0; j < 128; ++j) {
        float w = Wp[j * 64];
        #pragma unroll
        for (int n = 0; n < 8; ++n) acc[n] += hs[n][j] * w;
    }
    const float as = aheads[hd * 128 + f];
    const float ad = aheads[hd * 128 + 64 + f];
    #pragma unroll
    for (int n = 0; n < 8; ++n) {
        Wh[(size_t)(i0 + n) * 256 + hd * 64 + f] = acc[n];
        float sv = acc[n] * as, dv = acc[n] * ad;
        #pragma unroll
        for (int o = 32; o > 0; o >>= 1) {
            sv += __shfl_xor(sv, o, 64);
            dv += __shfl_xor(dv, o, 64);
        }
        if (f == 0) { src1[hd * GN + i0 + n] = sv; dst1[hd * GN + i0 + n] = dv; }
    }
}

// ===== layer-1 attention: one wave per ROW (all 4 heads), float4 gathers =====
__global__ __launch_bounds__(256) void attn1_kernel(
        const float* __restrict__ Wh, const float* __restrict__ src,
        const float* __restrict__ dst, const int* __restrict__ cnt,
        const int* __restrict__ idx, float* __restrict__ hcat) {
    __shared__ float ps[4][4][260];     // [wave][head][neighbor]
    const int wave = threadIdx.x >> 6;
    const int lane = threadIdx.x & 63;
    const int row  = blockIdx.x * 4 + wave;
    const int deg  = cnt[row];
    const int* nb  = idx + (size_t)row * MAX_DEG;
    const int nchunk = (deg + 63) >> 6;

    #pragma unroll
    for (int hd = 0; hd < 4; ++hd) {
        const float s_i = src[hd * GN + row];
        float e[4];
        float m = -1e30f;
        for (int c = 0; c < nchunk; ++c) {
            int t = c * 64 + lane;
            float ev = -1e30f;
            if (t < deg) {
                int j = nb[t];
                ev = s_i + dst[hd * GN + j];
                ev = (ev > 0.0f) ? ev : ALPHA * ev;
            }
            e[c] = ev; m = fmaxf(m, ev);
        }
        #pragma unroll
        for (int o = 32; o > 0; o >>= 1) m = fmaxf(m, __shfl_xor(m, o, 64));
        float l = 0.0f;
        for (int c = 0; c < nchunk; ++c) { e[c] = expf(e[c] - m); l += e[c]; }
        #pragma unroll
        for (int o = 32; o > 0; o >>= 1) l += __shfl_xor(l, o, 64);
        float inv = 1.0f / l;
        for (int c = 0; c < nchunk; ++c) ps[wave][hd][c * 64 + lane] = e[c] * inv;
    }

    const int hl = lane >> 4;
    const float4* Wh4 = (const float4*)Wh;
    float4 acc = make_float4(0.f, 0.f, 0.f, 0.f);
    const int deg4 = (deg + 3) & ~3;
    for (int t = 0; t < deg4; t += 4) {
        int4 jj = *(const int4*)(nb + t);
        float p0 = ps[wave][hl][t],     p1 = ps[wave][hl][t + 1];
        float p2 = ps[wave][hl][t + 2], p3 = ps[wave][hl][t + 3];
        float4 v0 = Wh4[(size_t)jj.x * 64 + lane];
        float4 v1 = Wh4[(size_t)jj.y * 64 + lane];
        float4 v2 = Wh4[(size_t)jj.z * 64 + lane];
        float4 v3 = Wh4[(size_t)jj.w * 64 + lane];
        acc.x += p0 * v0.x + p1 * v1.x + p2 * v2.x + p3 * v3.x;
        acc.y += p0 * v0.y + p1 * v1.y + p2 * v2.y + p3 * v3.y;
        acc.z += p0 * v0.z + p1 * v1.z + p2 * v2.z + p3 * v3.z;
        acc.w += p0 * v0.w + p1 * v1.w + p2 * v2.w + p3 * v3.w;
    }
    acc.x = (acc.x > 0.0f) ? acc.x : expm1f(acc.x);
    acc.y = (acc.y > 0.0f) ? acc.y : expm1f(acc.y);
    acc.z = (acc.z > 0.0f) ? acc.z : expm1f(acc.z);
    acc.w = (acc.w > 0.0f) ? acc.w : expm1f(acc.w);
    ((float4*)hcat)[(size_t)row * 64 + lane] = acc;
}

// ===== fused: Wh2 = hcat@W_end ; src2/dst2 =====
__global__ __launch_bounds__(256) void fused2_kernel(
        const float* __restrict__ hcat, const float* __restrict__ Wend,
        const float* __restrict__ aend, float* __restrict__ Wh2,
        float* __restrict__ src2, float* __restrict__ dst2) {
    __shared__ float cs[8][256];
    const int tid = threadIdx.x;
    const int i0  = blockIdx.x * 8;
    #pragma unroll
    for (int t = 0; t < 8; ++t) {
        int e = t * 256 + tid;
        cs[e >> 8][e & 255] = hcat[(size_t)i0 * 256 + e];
    }
    __syncthreads();
    const int f = tid & 63;
    const int n0 = tid >> 6;
    float a0 = 0.0f, a1 = 0.0f;
    const float* Wp = Wend + f;
    for (int j = 0; j < 256; ++j) {
        float w = Wp[j * 64];
        a0 += cs[n0][j] * w;
        a1 += cs[n0 + 4][j] * w;
    }
    const float as = aend[f];
    const float ad = aend[64 + f];
    Wh2[(size_t)(i0 + n0) * 64 + f] = a0;
    Wh2[(size_t)(i0 + n0 + 4) * 64 + f] = a1;
    float s0 = a0 * as, d0 = a0 * ad, s1 = a1 * as, d1 = a1 * ad;
    #pragma unroll
    for (int o = 32; o > 0; o >>= 1) {
        s0 += __shfl_xor(s0, o, 64); d0 += __shfl_xor(d0, o, 64);
        s1 += __shfl_xor(s1, o, 64); d1 += __shfl_xor(d1, o, 64);
    }
    if (f == 0) {
        src2[i0 + n0] = s0; dst2[i0 + n0] = d0;
        src2[i0 + n0 + 4] = s1; dst2[i0 + n0 + 4] = d1;
    }
}

// ===== layer-2 attention + elu + final row softmax; wave per row =====
__global__ __launch_bounds__(256) void attn2_kernel(
        const float* __restrict__ Wh2, const float* __restrict__ src,
        const float* __restrict__ dst, const int* __restrict__ cnt,
        const int* __restrict__ idx, float* __restrict__ out) {
    const int wave = threadIdx.x >> 6;
    const int lane = threadIdx.x & 63;
    const int row  = blockIdx.x * 4 + wave;
    const int deg = cnt[row];
    const int* nb = idx + (size_t)row * MAX_DEG;
    const float s_i = src[row];

    float e[4];
    #pragma unroll
    for (int c = 0; c < 4; ++c) {
        int t = c * 64 + lane;
        float ev = -1e30f;
        if (t < deg) {
            int j = nb[t];
            ev = s_i + dst[j];
            ev = (ev > 0.0f) ? ev : ALPHA * ev;
        }
        e[c] = ev;
    }
    float m = fmaxf(fmaxf(e[0], e[1]), fmaxf(e[2], e[3]));
    #pragma unroll
    for (int o = 32; o > 0; o >>= 1) m = fmaxf(m, __shfl_xor(m, o, 64));
    float l = 0.0f;
    #pragma unroll
    for (int c = 0; c < 4; ++c) { e[c] = expf(e[c] - m); l += e[c]; }
    #pragma unroll
    for (int o = 32; o > 0; o >>= 1) l += __shfl_xor(l, o, 64);

    float accA = 0.0f, accB = 0.0f;
    const float* W2 = Wh2 + lane;
    #pragma unroll
    for (int c = 0; c < 4; ++c) {
        int base = c * 64;
        if (base >= deg) break;
        int nmax = deg - base; if (nmax > 64) nmax = 64;
        int n4 = (nmax + 3) & ~3;
        for (int t = 0; t < n4; t += 4) {
            float p0 = __shfl(e[c], t, 64);
            float p1 = __shfl(e[c], t + 1, 64);
            float p2 = __shfl(e[c], t + 2, 64);
            float p3 = __shfl(e[c], t + 3, 64);
            int4 jj = *(const int4*)(nb + base + t);
            accA += p0 * W2[(size_t)jj.x * 64];
            accB += p1 * W2[(size_t)jj.y * 64];
            accA += p2 * W2[(size_t)jj.z * 64];
            accB += p3 * W2[(size_t)jj.w * 64];
        }
    }
    float v = (accA + accB) / l;
    v = (v > 0.0f) ? v : expm1f(v);      // elu

    float mm = v;
    #pragma unroll
    for (int o = 32; o > 0; o >>= 1) mm = fmaxf(mm, __shfl_xor(mm, o, 64));
    float ee = expf(v - mm);
    float ss = ee;
    #pragma unroll
    for (int o = 32; o > 0; o >>= 1) ss += __shfl_xor(ss, o, 64);
    out[(size_t)row * F_OUT + lane] = ee / ss;
}

extern "C" void kernel_launch(void* const* d_in, const int* in_sizes, int n_in,
                              void* d_out, int out_size, void* d_ws, size_t ws_size,
                              hipStream_t stream) {
    const float* x      = (const float*)d_in[0];
    const float* adj    = (const float*)d_in[1];
    const float* lin_W  = (const float*)d_in[2];
    const float* lin_b  = (const float*)d_in[3];
    const float* Wheads = (const float*)d_in[4];
    const float* aheads = (const float*)d_in[5];
    const float* Wend   = (const float*)d_in[6];
    const float* aend   = (const float*)d_in[7];
    float* out = (float*)d_out;

    char* ws = (char*)d_ws;
    float* Wh   = (float*)(ws + OFF_WH);
    float* src1 = (float*)(ws + OFF_SRC1);
    float* dst1 = (float*)(ws + OFF_DST1);
    float* hcat = (float*)(ws + OFF_HCAT);
    float* Wh2  = (float*)(ws + OFF_WH2);
    float* src2 = (float*)(ws + OFF_SRC2);
    float* dst2 = (float*)(ws + OFF_DST2);
    int*   cnt  = (int*)(ws + OFF_CNT);
    int*   nidx = (int*)(ws + OFF_IDX);

    build_nbr_kernel<<<GN, 256, 0, stream>>>(adj, cnt, nidx);
    fused1_kernel<<<GN / 8, 256, 0, stream>>>(x, lin_W, lin_b, Wheads, aheads, Wh, src1, dst1);
    attn1_kernel<<<GN / 4, 256, 0, stream>>>(Wh, src1, dst1, cnt, nidx, hcat);
    fused2_kernel<<<GN / 8, 256, 0, stream>>>(hcat, Wend, aend, Wh2, src2, dst2);
    attn2_kernel<<<GN / 4, 256, 0, stream>>>(Wh2, src2, dst2, cnt, nidx, out);
}